// Round 1
// baseline (141.160 us; speedup 1.0000x reference)
//
#include <hip/hip_runtime.h>

#define PNUM 128
#define BATCH 8192

// Branchless smooth-L1: for m = min(|d|,1):  0.5*m*m + (|d| - m)
//  |d|<1 -> 0.5 d^2 ;  |d|>=1 -> 0.5 + |d| - 1 = |d| - 0.5
__device__ __forceinline__ float sl1(float d) {
    float a = fabsf(d);
    float m = fminf(a, 1.0f);
    return fmaf(0.5f * m, m, a - m);
}

// One block per (batch, pred) pair. 128 threads; thread i owns cyclic shift i.
__global__ __launch_bounds__(PNUM) void match_stage1(
        const float* __restrict__ pred0,
        const float* __restrict__ pred1,
        const float* __restrict__ gt,
        float* __restrict__ ws) {
    __shared__ float2 sp[PNUM];          // pred points
    __shared__ float2 sg[2 * PNUM];      // gt points, doubled to avoid % in loop

    const int bid = blockIdx.x;
    const int b   = bid >> 1;
    const float* pred = (bid & 1) ? pred1 : pred0;
    const int t = threadIdx.x;

    const float2* pv = (const float2*)(pred + (size_t)b * PNUM * 2);
    const float2* gv = (const float2*)(gt   + (size_t)b * PNUM * 2);

    sp[t] = pv[t];
    float2 g = gv[t];
    sg[t] = g;
    sg[t + PNUM] = g;
    __syncthreads();

    // S[t] = sum_j sl1(pred[j] - gt[(t+j) mod 128]) over both coords
    float acc = 0.f;
    const float2* gp = &sg[t];
#pragma unroll
    for (int j = 0; j < PNUM; ++j) {
        float2 p = sp[j];   // wave-uniform broadcast read
        float2 q = gp[j];   // per-lane read, immediate offset (doubled array)
        acc += sl1(p.x - q.x) + sl1(p.y - q.y);
    }

    // min over 128 shifts: butterfly within each wave (64 lanes), then combine 2 waves
#pragma unroll
    for (int m = 32; m > 0; m >>= 1)
        acc = fminf(acc, __shfl_xor(acc, m, 64));

    __shared__ float wmin[2];
    if ((t & 63) == 0) wmin[t >> 6] = acc;
    __syncthreads();
    if (t == 0) ws[bid] = fminf(wmin[0], wmin[1]);
}

// Sum the 16384 per-block mins, apply scale, write scalar.
__global__ __launch_bounds__(256) void match_stage2(
        const float* __restrict__ ws, float* __restrict__ out) {
    const int t = threadIdx.x;
    float s = 0.f;
    for (int i = t; i < 2 * BATCH; i += 256) s += ws[i];
#pragma unroll
    for (int m = 32; m > 0; m >>= 1) s += __shfl_xor(s, m, 64);

    __shared__ float wsum[4];
    if ((t & 63) == 0) wsum[t >> 6] = s;
    __syncthreads();
    if (t == 0) {
        float tot = wsum[0] + wsum[1] + wsum[2] + wsum[3];
        // mean over j (1/PNUM), mean over batch (1/BATCH), avg of two preds (1/2)
        out[0] = tot * (1.0f / (2.0f * BATCH * PNUM));
    }
}

extern "C" void kernel_launch(void* const* d_in, const int* in_sizes, int n_in,
                              void* d_out, int out_size, void* d_ws, size_t ws_size,
                              hipStream_t stream) {
    const float* pred0 = (const float*)d_in[0];
    const float* pred1 = (const float*)d_in[1];
    const float* gt    = (const float*)d_in[2];
    float* out = (float*)d_out;
    float* ws  = (float*)d_ws;   // 2*BATCH floats = 64 KiB

    match_stage1<<<2 * BATCH, PNUM, 0, stream>>>(pred0, pred1, gt, ws);
    match_stage2<<<1, 256, 0, stream>>>(ws, out);
}